// Round 2
// baseline (190.418 us; speedup 1.0000x reference)
//
#include <hip/hip_runtime.h>
#include <hip/hip_bf16.h>

// TAttention: B=16, C=32, N=1024, T=128, R=10
//  k[b,n,t]   = sum_c alpha[c] * x[b,c,n,t]
//  kw1[b,t,r] = sum_n k[b,n,t] * W1[r,n]   (same for kw2/W2)
//  scores[b,t,s] = sum_r kw1[t,r]*kw2[s,r]; att = softmax_s  (bf16)
//  out[b,c,n,t] = sum_s att[b,t,s] * x[b,c,n,s]   <- MFMA bf16, memory-bound
//
// HBM floor: read x 2x (512 MiB) + write out (256 MiB) ~= 118 us @ 6.8 TB/s.

#define B_ 16
#define C_ 32
#define N_ 1024
#define T_ 128
#define R_ 10
#define CH_ 16          // n-chunks for kw partials
#define NCH_ (N_ / CH_) // 64 n per chunk

typedef __bf16 bf16x8 __attribute__((ext_vector_type(8)));
typedef __bf16 bf16x4 __attribute__((ext_vector_type(4)));
typedef float f32x4 __attribute__((ext_vector_type(4)));

// ---------------------------------------------------------------- kernel 1
// k[b][n][t] = sum_c alpha[c] * x[b][c][n][t]; float4 over t, coalesced.
__global__ __launch_bounds__(256) void k_reduce_c(const float* __restrict__ x,
                                                  const float* __restrict__ alpha,
                                                  float* __restrict__ k) {
    int bid = blockIdx.x;            // B * N/8 = 2048
    int b   = bid >> 7;
    int nc  = bid & 127;
    int tid = threadIdx.x;
    int nl  = tid >> 5;              // 0..7
    int lc  = tid & 31;              // 32 lanes * float4 = 128 t
    int n   = nc * 8 + nl;
    const float4* xb = reinterpret_cast<const float4*>(
        x + ((size_t)(b * C_) * N_ + n) * T_) + lc;
    float4 acc = {0.f, 0.f, 0.f, 0.f};
    #pragma unroll 8
    for (int c = 0; c < C_; ++c) {
        float a = alpha[c];
        float4 v = xb[(size_t)c * (N_ * T_ / 4)];
        acc.x += a * v.x; acc.y += a * v.y; acc.z += a * v.z; acc.w += a * v.w;
    }
    reinterpret_cast<float4*>(k + ((size_t)b * N_ + n) * T_)[lc] = acc;
}

// ---------------------------------------------------------------- kernel 2
// per n-chunk partial kw: p1[b][ch][t][r] = sum_{n in chunk} k[b,n,t]*W1[r,n]
__global__ __launch_bounds__(128) void kw_partial(const float* __restrict__ k,
                                                  const float* __restrict__ W1,
                                                  const float* __restrict__ W2,
                                                  float* __restrict__ p1,
                                                  float* __restrict__ p2) {
    __shared__ __align__(16) float ws[NCH_][20];   // [n_local][r: 10 W1 | 10 W2]
    int bid = blockIdx.x;    // B * CH_
    int b   = bid >> 4;
    int ch  = bid & (CH_ - 1);
    int n0  = ch * NCH_;
    int t   = threadIdx.x;
    for (int i = t; i < NCH_ * R_; i += 128) {
        int r = i / NCH_, nl = i % NCH_;
        ws[nl][r]      = W1[r * N_ + n0 + nl];
        ws[nl][R_ + r] = W2[r * N_ + n0 + nl];
    }
    __syncthreads();
    float a1[R_] = {}, a2[R_] = {};
    const float* kb = k + ((size_t)b * N_ + n0) * T_ + t;
    for (int nl = 0; nl < NCH_; ++nl) {
        float kv = kb[nl * T_];
        float wv[20];
        const float4* wr = reinterpret_cast<const float4*>(&ws[nl][0]);
        #pragma unroll
        for (int q = 0; q < 5; ++q) *reinterpret_cast<float4*>(&wv[q * 4]) = wr[q];
        #pragma unroll
        for (int r = 0; r < R_; ++r) {
            a1[r] += kv * wv[r];
            a2[r] += kv * wv[R_ + r];
        }
    }
    size_t o = ((size_t)(b * CH_ + ch) * T_ + t) * R_;
    #pragma unroll
    for (int r = 0; r < R_; ++r) { p1[o + r] = a1[r]; p2[o + r] = a2[r]; }
}

// ---------------------------------------------------------------- kernel 3
// reduce partials, scores, softmax (f32), write att[b][t][s] as bf16 rows
__global__ __launch_bounds__(128) void scores_softmax(const float* __restrict__ p1,
                                                      const float* __restrict__ p2,
                                                      __bf16* __restrict__ att) {
    __shared__ __align__(16) float kw1s[T_][12];
    __shared__ __align__(16) float kw2s[T_][12];
    __shared__ float sc[T_][T_ + 1];
    int b = blockIdx.x;
    int t = threadIdx.x;
    #pragma unroll
    for (int r = 0; r < R_; ++r) {
        float s1 = 0.f, s2 = 0.f;
        for (int ch = 0; ch < CH_; ++ch) {
            size_t o = ((size_t)(b * CH_ + ch) * T_ + t) * R_ + r;
            s1 += p1[o]; s2 += p2[o];
        }
        kw1s[t][r] = s1; kw2s[t][r] = s2;
    }
    __syncthreads();
    float myw[R_];
    #pragma unroll
    for (int r = 0; r < R_; ++r) myw[r] = kw1s[t][r];
    float mx = -1e30f;
    for (int s = 0; s < T_; ++s) {
        float wv[12];
        const float4* qr = reinterpret_cast<const float4*>(&kw2s[s][0]);
        #pragma unroll
        for (int q = 0; q < 3; ++q) *reinterpret_cast<float4*>(&wv[q * 4]) = qr[q];
        float v = 0.f;
        #pragma unroll
        for (int r = 0; r < R_; ++r) v += myw[r] * wv[r];
        sc[t][s] = v;
        mx = fmaxf(mx, v);
    }
    float sum = 0.f;
    for (int s = 0; s < T_; ++s) {
        float e = __expf(sc[t][s] - mx);
        sc[t][s] = e;
        sum += e;
    }
    float inv = 1.0f / sum;
    // vectorized own-row store: att[b][t][s], inv fused
    __bf16* arow = att + ((size_t)b * T_ + t) * T_;
    for (int s8 = 0; s8 < T_; s8 += 8) {
        bf16x8 h;
        #pragma unroll
        for (int q = 0; q < 8; ++q) h[q] = (__bf16)(sc[t][s8 + q] * inv);
        *reinterpret_cast<bf16x8*>(arow + s8) = h;
    }
}

// ---------------------------------------------------------------- kernel 4
// out[n,t] = sum_s att[t,s]*x[n,s] per (b,c,64n) slab; MFMA 16x16x32 bf16.
// A = att (D rows = t -> float4 stores), B = x (D cols = n).
// LDS XOR-swizzle byte ^= ((row&7)<<4) on both tiles (T2, bank-conflict-free).
__global__ __launch_bounds__(256) void out_gemm(const float* __restrict__ x,
                                                const __bf16* __restrict__ att,
                                                float* __restrict__ out) {
    __shared__ __align__(16) __bf16 attl[T_][T_];  // 32 KB, swizzled
    __shared__ __align__(16) __bf16 xsl[64][T_];   // 16 KB, swizzled
    int bid = blockIdx.x;          // B*C*(N/64) = 8192
    int nc  = bid & 15;
    int c   = (bid >> 4) & 31;
    int b   = bid >> 9;
    int tid = threadIdx.x;
    size_t slab = ((size_t)(b * C_ + c) * N_ + nc * 64) * T_;
    char* attb = reinterpret_cast<char*>(&attl[0][0]);
    char* xb   = reinterpret_cast<char*>(&xsl[0][0]);

    // stage att[b] (bf16, 32KB) -> LDS, swizzled
    const uint4* ga = reinterpret_cast<const uint4*>(att + (size_t)b * T_ * T_);
    #pragma unroll
    for (int i = 0; i < 8; ++i) {
        int e   = i * 256 + tid;             // uint4 = 8 bf16; 16 per row
        int row = e >> 4;
        int bc  = ((e & 15) * 16) ^ ((row & 7) << 4);
        *reinterpret_cast<uint4*>(attb + row * 256 + bc) = ga[e];
    }
    // stage x slab (f32 32KB) -> bf16 LDS, swizzled
    const float4* gx = reinterpret_cast<const float4*>(x + slab);
    #pragma unroll
    for (int i = 0; i < 8; ++i) {
        int e   = i * 256 + tid;             // float4; 32 per row
        int row = e >> 5;
        float4 v = gx[e];
        bf16x4 h = {(__bf16)v.x, (__bf16)v.y, (__bf16)v.z, (__bf16)v.w};
        int bc = ((e & 31) * 8) ^ ((row & 7) << 4);
        *reinterpret_cast<bf16x4*>(xb + row * 256 + bc) = h;
    }
    __syncthreads();

    int wave = tid >> 6, lane = tid & 63;
    int r16 = lane & 15, g = lane >> 4;
    int wt = wave & 1, wn = wave >> 1;       // wave tile: 64t x 32n
    int swz = (r16 & 7) << 4;
    f32x4 acc[2][4] = {};
    #pragma unroll
    for (int ks = 0; ks < 4; ++ks) {
        int kc = ks * 64 + g * 16;           // byte col of 16B k-fragment
        bf16x8 a[4], bx[2];
        #pragma unroll
        for (int tt = 0; tt < 4; ++tt) {     // A = att rows (t)
            int row = wt * 64 + tt * 16 + r16;
            a[tt] = *reinterpret_cast<const bf16x8*>(attb + row * 256 + (kc ^ swz));
        }
        #pragma unroll
        for (int nn = 0; nn < 2; ++nn) {     // B = x rows (n)
            int row = wn * 32 + nn * 16 + r16;
            bx[nn] = *reinterpret_cast<const bf16x8*>(xb + row * 256 + (kc ^ swz));
        }
        #pragma unroll
        for (int nn = 0; nn < 2; ++nn)
            #pragma unroll
            for (int tt = 0; tt < 4; ++tt)
                acc[nn][tt] = __builtin_amdgcn_mfma_f32_16x16x32_bf16(
                    a[tt], bx[nn], acc[nn][tt], 0, 0, 0);
    }
    // D: col = lane&15 -> n, row = (lane>>4)*4+j -> t  => float4 along t
    float* o = out + slab;
    #pragma unroll
    for (int nn = 0; nn < 2; ++nn) {
        int n_l = wn * 32 + nn * 16 + r16;
        #pragma unroll
        for (int tt = 0; tt < 4; ++tt) {
            int t_l = wt * 64 + tt * 16 + g * 4;
            *reinterpret_cast<f32x4*>(o + (size_t)n_l * T_ + t_l) = acc[nn][tt];
        }
    }
}

// ----------------------------------------------------------------
extern "C" void kernel_launch(void* const* d_in, const int* in_sizes, int n_in,
                              void* d_out, int out_size, void* d_ws, size_t ws_size,
                              hipStream_t stream) {
    const float* x     = (const float*)d_in[0];
    const float* W1    = (const float*)d_in[1];
    const float* W2    = (const float*)d_in[2];
    const float* alpha = (const float*)d_in[3];
    float* out = (float*)d_out;

    float* k  = (float*)d_ws;                           // 16*1024*128 f32 = 8 MB
    float* p1 = k + (size_t)B_ * N_ * T_;               // 16*16*128*10 f32
    float* p2 = p1 + (size_t)B_ * CH_ * T_ * R_;
    __bf16* att = (__bf16*)(p2 + (size_t)B_ * CH_ * T_ * R_);  // 16*128*128 bf16

    k_reduce_c<<<dim3(B_ * (N_ / 8)), dim3(256), 0, stream>>>(x, alpha, k);
    kw_partial<<<dim3(B_ * CH_), dim3(128), 0, stream>>>(k, W1, W2, p1, p2);
    scores_softmax<<<dim3(B_), dim3(128), 0, stream>>>(p1, p2, att);
    out_gemm<<<dim3(B_ * C_ * (N_ / 64)), dim3(256), 0, stream>>>(x, att, out);
}